// Round 12
// baseline (172.771 us; speedup 1.0000x reference)
//
#include <hip/hip_runtime.h>

#define CAP 64
#define OVF_MAX 8192
#define CSH 4          // cur stride shift: 16 ints = one 64B line per counter

// ---------------- helpers ----------------

// Conflict-free stage of W (64x64 row-major) into LDS:
//   Wt[q*64 + l] = float4(W[4q][l], W[4q+1][l], W[4q+2][l], W[4q+3][l])
__device__ __forceinline__ void stage_W(const float* __restrict__ W,
                                        float4* __restrict__ Wt, int tid) {
    int l = tid & 63, qq = tid >> 6;
    #pragma unroll
    for (int s = 0; s < 4; ++s) {
        int q = qq * 4 + s;                 // 0..15
        float4 v = make_float4(W[(4 * q + 0) * 64 + l],
                               W[(4 * q + 1) * 64 + l],
                               W[(4 * q + 2) * 64 + l],
                               W[(4 * q + 3) * 64 + l]);
        Wt[q * 64 + l] = v;
    }
}

// Single-bucket gather: a0..a3 += in[src][c] * ew  (dinv pre-folded into in)
#define GATHER_BODY(in_, n_, c_, a0, a1, a2, a3, anyovf)                         \
    {                                                                            \
        int mfull = cur[(size_t)(n_) << CSH];                                    \
        int m = mfull > CAP ? CAP : mfull;                                       \
        anyovf = (mfull > CAP);                                                  \
        const int2* bkt = eb + (size_t)(n_) * CAP;                               \
        int i = 0;                                                               \
        for (; i + 8 <= m; i += 8) {                                             \
            int2 e0 = bkt[i + 0], e1 = bkt[i + 1], e2 = bkt[i + 2], e3 = bkt[i + 3]; \
            int2 e4 = bkt[i + 4], e5 = bkt[i + 5], e6 = bkt[i + 6], e7 = bkt[i + 7]; \
            float v0 = in_[(size_t)e0.x * 64 + (c_)], v1 = in_[(size_t)e1.x * 64 + (c_)]; \
            float v2 = in_[(size_t)e2.x * 64 + (c_)], v3 = in_[(size_t)e3.x * 64 + (c_)]; \
            float v4 = in_[(size_t)e4.x * 64 + (c_)], v5 = in_[(size_t)e5.x * 64 + (c_)]; \
            float v6 = in_[(size_t)e6.x * 64 + (c_)], v7 = in_[(size_t)e7.x * 64 + (c_)]; \
            a0 = fmaf(v0, __int_as_float(e0.y), a0);                             \
            a1 = fmaf(v1, __int_as_float(e1.y), a1);                             \
            a2 = fmaf(v2, __int_as_float(e2.y), a2);                             \
            a3 = fmaf(v3, __int_as_float(e3.y), a3);                             \
            a0 = fmaf(v4, __int_as_float(e4.y), a0);                             \
            a1 = fmaf(v5, __int_as_float(e5.y), a1);                             \
            a2 = fmaf(v6, __int_as_float(e6.y), a2);                             \
            a3 = fmaf(v7, __int_as_float(e7.y), a3);                             \
        }                                                                        \
        for (; i < m; ++i) {                                                     \
            int2 e = bkt[i];                                                     \
            a0 = fmaf(in_[(size_t)e.x * 64 + (c_)], __int_as_float(e.y), a0);    \
        }                                                                        \
        if (anyovf) {                                                            \
            int oc = *ovf_cnt; if (oc > OVF_MAX) oc = OVF_MAX;                   \
            for (int k = 0; k < oc; ++k) {                                       \
                int4 o = ovf[k];                                                 \
                if (o.y == (n_))                                                 \
                    a0 = fmaf(in_[(size_t)o.x * 64 + (c_)], __int_as_float(o.z), a0); \
            }                                                                    \
        }                                                                        \
    }

// ---------------- kernels ----------------

// Prelude: zero cur (padded) / ovfc; compact ewc = ea[:,15]; Wc = W2@Wout; bc.
__global__ void k_pre(int* __restrict__ cur, int* __restrict__ ovfc, int N,
                      const float* __restrict__ ea, float* __restrict__ ewc, int E,
                      const float* __restrict__ W2, const float* __restrict__ Wout,
                      const float* __restrict__ b2, const float* __restrict__ bout,
                      float* __restrict__ Wc, float* __restrict__ bc, int zb) {
    int tid = threadIdx.x;
    int bid = blockIdx.x;
    if (bid < zb) {
        int i = bid * 256 + tid;
        if (i < (N << CSH)) cur[i] = 0;
        if (i == (N << CSH)) *ovfc = 0;
        return;
    }
    if (bid < zb + 17) {
        int wb = bid - zb;
        if (wb < 16) {
            int idx = wb * 256 + tid;
            int j = idx >> 6, i = idx & 63;
            float s = 0.0f;
            #pragma unroll 8
            for (int m = 0; m < 64; ++m)
                s = fmaf(W2[i * 64 + m], Wout[m * 64 + j], s);
            Wc[i * 64 + j] = s;
        } else if (tid < 64) {
            float s = bout[tid];
            for (int k = 0; k < 64; ++k)
                s = fmaf(b2[k], Wout[k * 64 + tid], s);
            bc[tid] = s;
        }
        return;
    }
    int e = (bid - zb - 17) * 256 + tid;     // ewc compaction (streaming)
    if (e < E) ewc[e] = ea[(size_t)e * 16 + 15];
}

// Fat kernel, parity-interleaved (R9/R11 proven config: 1 edge/thread):
//  even blocks: bucket edges by dst (compact ewc read, line-padded counters)
//  odd  blocks: h1 = mean_t(x) @ W1 (coalesced x, conflict-free LDS GEMM)
__global__ __launch_bounds__(256) void k_scatmean(
        const int* __restrict__ ei, const float* __restrict__ ewc,
        int* __restrict__ cur, int2* __restrict__ eb,
        int* __restrict__ ovf_cnt, int4* __restrict__ ovf,
        int E, int scatterBlocks,
        const float* __restrict__ x, const float* __restrict__ W1,
        float* __restrict__ h1, int N, int meanBlocks) {
    int tid = threadIdx.x;
    int bid = (int)blockIdx.x;
    int nmin = scatterBlocks < meanBlocks ? scatterBlocks : meanBlocks;
    int isScat, rid;
    if (bid < 2 * nmin) { isScat = !(bid & 1); rid = bid >> 1; }
    else { isScat = (scatterBlocks > meanBlocks); rid = bid - 2 * nmin + nmin; }

    if (isScat) {
        int e = rid * 256 + tid;
        if (e < E) {
            int s = ei[e];
            int d = ei[E + e];
            float w = ewc[e];
            int p = atomicAdd(cur + ((size_t)d << CSH), 1);   // one counter per line
            if (p < CAP) {
                eb[(size_t)d * CAP + p] = make_int2(s, __float_as_int(w));
            } else {
                int q = atomicAdd(ovf_cnt, 1);
                if (q < OVF_MAX) ovf[q] = make_int4(s, d, __float_as_int(w), 0);
            }
        }
        return;
    }
    __shared__ float4 Wt[16 * 64];           // 16KB, conflict-free layout
    __shared__ float rbuf[4 * 64];
    stage_W(W1, Wt, tid);
    __syncthreads();
    int w = tid >> 6, l = tid & 63;
    float* rw = rbuf + w * 64;
    for (int it = 0; it < 4; ++it) {         // NOT unrolled: keep VGPRs lean
        int n = rid * 16 + it * 4 + w;       // wave-uniform
        if (n >= N) continue;
        const float4* xp = (const float4*)(x + (size_t)n * 1024);
        float4 v0 = xp[l], v1 = xp[64 + l], v2 = xp[128 + l], v3 = xp[192 + l];
        float s0 = (v0.x + v0.y) + (v0.z + v0.w);
        float s1 = (v1.x + v1.y) + (v1.z + v1.w);
        float s2 = (v2.x + v2.y) + (v2.z + v2.w);
        float s3 = (v3.x + v3.y) + (v3.z + v3.w);
        s0 += __shfl_xor(s0, 1); s0 += __shfl_xor(s0, 2);
        s1 += __shfl_xor(s1, 1); s1 += __shfl_xor(s1, 2);
        s2 += __shfl_xor(s2, 1); s2 += __shfl_xor(s2, 2);
        s3 += __shfl_xor(s3, 1); s3 += __shfl_xor(s3, 2);
        if ((l & 3) == 0) {                  // quad leader: channels q,16+q,32+q,48+q
            int q = l >> 2;
            rw[q]      = s0 * 0.0625f;
            rw[q + 16] = s1 * 0.0625f;
            rw[q + 32] = s2 * 0.0625f;
            rw[q + 48] = s3 * 0.0625f;
        }
        float acc = 0.0f;
        const float4* rb4 = (const float4*)rw;
        #pragma unroll
        for (int q = 0; q < 16; ++q) {
            float4 rv = rb4[q];              // broadcast (same addr all lanes)
            float4 wv = Wt[q * 64 + l];      // contiguous: conflict-free
            acc = fmaf(rv.x, wv.x, acc);
            acc = fmaf(rv.y, wv.y, acc);
            acc = fmaf(rv.z, wv.z, acc);
            acc = fmaf(rv.w, wv.w, acc);
        }
        h1[(size_t)n * 64 + l] = acc;
    }
}

// Phase A: dinv[n] = 1/sqrt(1 + bucket ew sum), 4 lanes/node (64 nodes/block).
// Phase B: scale H1 *= dinv[n] in place (g-form: folds dinv[src] out of aggs).
__global__ __launch_bounds__(256) void k_dinvb(
        const int* __restrict__ cur, const int2* __restrict__ eb,
        const int* __restrict__ ovf_cnt, const int4* __restrict__ ovf,
        float* __restrict__ dinv, float* __restrict__ H1, int N) {
    __shared__ float sdv[64];
    int tid = threadIdx.x;
    int base = blockIdx.x * 64;
    int n = base + (tid >> 2);
    int j = tid & 3;
    if (n < N) {
        int mfull = cur[(size_t)n << CSH];
        int m = mfull > CAP ? CAP : mfull;
        float s = 0.0f;
        for (int i = j; i < m; i += 4) s += __int_as_float(eb[(size_t)n * CAP + i].y);
        s += __shfl_xor(s, 1);
        s += __shfl_xor(s, 2);
        if (j == 0) {
            if (mfull > CAP) {
                int oc = *ovf_cnt; if (oc > OVF_MAX) oc = OVF_MAX;
                for (int k = 0; k < oc; ++k) {
                    int4 o = ovf[k];
                    if (o.y == n) s += __int_as_float(o.z);
                }
            }
            float dv = 1.0f / sqrtf(s + 1.0f);
            dinv[n] = dv;
            sdv[tid >> 2] = dv;
        }
    }
    __syncthreads();
    // phase B: 64 nodes x 64 ch = 4096 elems, 256 threads x 16 iters, coalesced
    #pragma unroll
    for (int k = 0; k < 16; ++k) {
        int idx = k * 256 + tid;
        int ln = idx >> 6, ch = idx & 63;
        int nn = base + ln;
        if (nn < N) H1[(size_t)nn * 64 + ch] *= sdv[ln];
    }
}

// Layer-1: gather g=H1*dinv + bias + relu; writes Zg = relu(r)*dinv (g-form).
__global__ __launch_bounds__(256) void k_agg1(const float* __restrict__ in,
                                              const float* __restrict__ bias,
                                              const float* __restrict__ dinv,
                                              const int* __restrict__ cur,
                                              const int2* __restrict__ eb,
                                              const int* __restrict__ ovf_cnt,
                                              const int4* __restrict__ ovf,
                                              float* __restrict__ out, int N) {
    int tid = threadIdx.x;
    int w = tid >> 6, c = tid & 63;
    float bias_c = bias[c];
    for (int it = 0; it < 4; ++it) {
        int n = blockIdx.x * 16 + it * 4 + w;
        if (n >= N) continue;
        float dv = dinv[n];
        float gself = in[(size_t)n * 64 + c];     // already dinv-scaled
        float a0 = 0.f, a1 = 0.f, a2 = 0.f, a3 = 0.f;
        int anyovf;
        GATHER_BODY(in, n, c, a0, a1, a2, a3, anyovf)
        float r = fmaf(dv, ((a0 + a1) + (a2 + a3)) + gself, bias_c);
        r = fmaxf(r, 0.0f);
        out[(size_t)n * 64 + c] = r * dv;         // Zg for layer 2
    }
}

// Layer-2: gather Zg + conflict-free LDS GEMM (Wc) + bc -> final output.
__global__ __launch_bounds__(256) void k_agg2(const float* __restrict__ in,
                                              const float* __restrict__ Wc,
                                              const float* __restrict__ bc,
                                              const float* __restrict__ dinv,
                                              const int* __restrict__ cur,
                                              const int2* __restrict__ eb,
                                              const int* __restrict__ ovf_cnt,
                                              const int4* __restrict__ ovf,
                                              float* __restrict__ out, int N) {
    __shared__ float4 Wt[16 * 64];
    __shared__ float rbuf[4 * 64];
    int tid = threadIdx.x;
    stage_W(Wc, Wt, tid);
    __syncthreads();
    int w = tid >> 6, c = tid & 63;
    float bc_c = bc[c];
    float* rw = rbuf + w * 64;
    for (int it = 0; it < 4; ++it) {         // NOT unrolled
        int n = blockIdx.x * 16 + it * 4 + w;
        if (n >= N) continue;
        float dv = dinv[n];
        float gself = in[(size_t)n * 64 + c];     // Zg, already dinv-scaled
        float a0 = 0.f, a1 = 0.f, a2 = 0.f, a3 = 0.f;
        int anyovf;
        GATHER_BODY(in, n, c, a0, a1, a2, a3, anyovf)
        float r = dv * (((a0 + a1) + (a2 + a3)) + gself);
        rw[c] = r;
        float acc = bc_c;
        const float4* rb4 = (const float4*)rw;
        #pragma unroll
        for (int q = 0; q < 16; ++q) {
            float4 rv = rb4[q];              // broadcast
            float4 wv = Wt[q * 64 + c];      // contiguous: conflict-free
            acc = fmaf(rv.x, wv.x, acc);
            acc = fmaf(rv.y, wv.y, acc);
            acc = fmaf(rv.z, wv.z, acc);
            acc = fmaf(rv.w, wv.w, acc);
        }
        out[(size_t)n * 64 + c] = acc;
    }
}

// ---------------- launcher ----------------

extern "C" void kernel_launch(void* const* d_in, const int* in_sizes, int n_in,
                              void* d_out, int out_size, void* d_ws, size_t ws_size,
                              hipStream_t stream) {
    const float* x    = (const float*)d_in[0];
    const int*   ei   = (const int*)d_in[1];
    const float* ea   = (const float*)d_in[2];
    const float* W1   = (const float*)d_in[3];
    const float* b1   = (const float*)d_in[4];
    const float* W2   = (const float*)d_in[5];
    const float* b2   = (const float*)d_in[6];
    const float* Wout = (const float*)d_in[7];
    const float* bout = (const float*)d_in[8];
    float* out = (float*)d_out;

    const int N = in_sizes[0] / (64 * 16);   // 50000
    const int E = in_sizes[1] / 2;           // 800000

    // workspace layout
    char* wsb = (char*)d_ws;
    int4*  ovf  = (int4*)wsb;                       // 128KB
    int2*  eb   = (int2*)(wsb + OVF_MAX * 16);      // N*CAP*8B = 25.6MB
    float* H1   = (float*)(wsb + OVF_MAX * 16 + (size_t)N * CAP * 8);
    size_t NC = (size_t)N * 64;
    float* Zg   = H1 + NC;
    int*   cur  = (int*)(Zg + NC);                  // N<<CSH ints (3.2MB padded)
    float* dinv = (float*)(cur + ((size_t)N << CSH));
    int*   ovfc = (int*)(dinv + N);
    float* Wc   = (float*)(ovfc + 4);
    float* bc   = Wc + 4096;
    float* ewc  = bc + 64;                          // E floats

    dim3 b256(256);
    int meanBlocks    = (N + 15) / 16;       // 3125
    int scatterBlocks = (E + 255) / 256;     // 3125 (1 edge/thread — proven config)
    int eaBlocks      = (E + 255) / 256;     // ewc compaction
    int zb = ((N << CSH) + 256) / 256;       // covers i == N<<CSH too

    hipLaunchKernelGGL(k_pre, dim3(zb + 17 + eaBlocks), b256, 0, stream,
                       cur, ovfc, N, ea, ewc, E, W2, Wout, b2, bout, Wc, bc, zb);
    hipLaunchKernelGGL(k_scatmean, dim3(scatterBlocks + meanBlocks), b256, 0, stream,
                       ei, ewc, cur, eb, ovfc, ovf, E, scatterBlocks, x, W1, H1, N, meanBlocks);
    hipLaunchKernelGGL(k_dinvb, dim3((N + 63) / 64), b256, 0, stream,
                       cur, eb, ovfc, ovf, dinv, H1, N);
    // layer 1: Zg = relu(dv*(Σ g[src]*ew + g[n]) + b1) * dv
    hipLaunchKernelGGL(k_agg1, dim3(meanBlocks), b256, 0, stream,
                       H1, b1, dinv, cur, eb, ovfc, ovf, Zg, N);
    // layer 2+out: out = (dv*(Σ Zg[src]*ew + Zg[n])) @ Wc + bc
    hipLaunchKernelGGL(k_agg2, dim3(meanBlocks), b256, 0, stream,
                       Zg, Wc, bc, dinv, cur, eb, ovfc, ovf, out, N);
}

// Round 13
// 169.566 us; speedup vs baseline: 1.0189x; 1.0189x over previous
//
#include <hip/hip_runtime.h>

#define CAP 64
#define OVF_MAX 8192

// ---------------- helpers ----------------

// Conflict-free stage of W (64x64 row-major) into LDS:
//   Wt[q*64 + l] = float4(W[4q][l], W[4q+1][l], W[4q+2][l], W[4q+3][l])
__device__ __forceinline__ void stage_W(const float* __restrict__ W,
                                        float4* __restrict__ Wt, int tid) {
    int l = tid & 63, qq = tid >> 6;
    #pragma unroll
    for (int s = 0; s < 4; ++s) {
        int q = qq * 4 + s;                 // 0..15
        float4 v = make_float4(W[(4 * q + 0) * 64 + l],
                               W[(4 * q + 1) * 64 + l],
                               W[(4 * q + 2) * 64 + l],
                               W[(4 * q + 3) * 64 + l]);
        Wt[q * 64 + l] = v;
    }
}

// Single-bucket gather: a0..a3 += in[src][c] * ew  (dinv pre-folded into in)
#define GATHER_BODY(in_, n_, c_, a0, a1, a2, a3, anyovf)                         \
    {                                                                            \
        int mfull = cur[(n_)];                                                   \
        int m = mfull > CAP ? CAP : mfull;                                       \
        anyovf = (mfull > CAP);                                                  \
        const int2* bkt = eb + (size_t)(n_) * CAP;                               \
        int i = 0;                                                               \
        for (; i + 8 <= m; i += 8) {                                             \
            int2 e0 = bkt[i + 0], e1 = bkt[i + 1], e2 = bkt[i + 2], e3 = bkt[i + 3]; \
            int2 e4 = bkt[i + 4], e5 = bkt[i + 5], e6 = bkt[i + 6], e7 = bkt[i + 7]; \
            float v0 = in_[(size_t)e0.x * 64 + (c_)], v1 = in_[(size_t)e1.x * 64 + (c_)]; \
            float v2 = in_[(size_t)e2.x * 64 + (c_)], v3 = in_[(size_t)e3.x * 64 + (c_)]; \
            float v4 = in_[(size_t)e4.x * 64 + (c_)], v5 = in_[(size_t)e5.x * 64 + (c_)]; \
            float v6 = in_[(size_t)e6.x * 64 + (c_)], v7 = in_[(size_t)e7.x * 64 + (c_)]; \
            a0 = fmaf(v0, __int_as_float(e0.y), a0);                             \
            a1 = fmaf(v1, __int_as_float(e1.y), a1);                             \
            a2 = fmaf(v2, __int_as_float(e2.y), a2);                             \
            a3 = fmaf(v3, __int_as_float(e3.y), a3);                             \
            a0 = fmaf(v4, __int_as_float(e4.y), a0);                             \
            a1 = fmaf(v5, __int_as_float(e5.y), a1);                             \
            a2 = fmaf(v6, __int_as_float(e6.y), a2);                             \
            a3 = fmaf(v7, __int_as_float(e7.y), a3);                             \
        }                                                                        \
        for (; i < m; ++i) {                                                     \
            int2 e = bkt[i];                                                     \
            a0 = fmaf(in_[(size_t)e.x * 64 + (c_)], __int_as_float(e.y), a0);    \
        }                                                                        \
        if (anyovf) {                                                            \
            int oc = *ovf_cnt; if (oc > OVF_MAX) oc = OVF_MAX;                   \
            for (int k = 0; k < oc; ++k) {                                       \
                int4 o = ovf[k];                                                 \
                if (o.y == (n_))                                                 \
                    a0 = fmaf(in_[(size_t)o.x * 64 + (c_)], __int_as_float(o.z), a0); \
            }                                                                    \
        }                                                                        \
    }

// ---------------- kernels ----------------

// Fat kernel, parity-interleaved (1 edge/thread — proven config):
//  even blocks:  bucket edges by dst (ea read directly: sequential 64B-line stream)
//  odd  blocks:  h1 = mean_t(x) @ W1 (coalesced x, conflict-free LDS GEMM)
//  17 trailing blocks: Wc = W2@Wout, bc = b2@Wout + bout (needed only by agg2)
__global__ __launch_bounds__(256) void k_scatmean(
        const int* __restrict__ ei, const float* __restrict__ ea,
        int* __restrict__ cur, int2* __restrict__ eb,
        int* __restrict__ ovf_cnt, int4* __restrict__ ovf,
        int E, int scatterBlocks,
        const float* __restrict__ x, const float* __restrict__ W1,
        float* __restrict__ h1, int N, int meanBlocks,
        const float* __restrict__ W2, const float* __restrict__ Wout,
        const float* __restrict__ b2, const float* __restrict__ bout,
        float* __restrict__ Wc, float* __restrict__ bc) {
    int tid = threadIdx.x;
    int bid = (int)blockIdx.x;
    int total_sm = scatterBlocks + meanBlocks;
    if (bid >= total_sm) {                   // Wc / bc tail blocks
        int wb = bid - total_sm;
        if (wb < 16) {
            int idx = wb * 256 + tid;
            int j = idx >> 6, i = idx & 63;
            float s = 0.0f;
            #pragma unroll 8
            for (int m = 0; m < 64; ++m)
                s = fmaf(W2[i * 64 + m], Wout[m * 64 + j], s);
            Wc[i * 64 + j] = s;
        } else if (tid < 64) {
            float s = bout[tid];
            for (int k = 0; k < 64; ++k)
                s = fmaf(b2[k], Wout[k * 64 + tid], s);
            bc[tid] = s;
        }
        return;
    }
    int nmin = scatterBlocks < meanBlocks ? scatterBlocks : meanBlocks;
    int isScat, rid;
    if (bid < 2 * nmin) { isScat = !(bid & 1); rid = bid >> 1; }
    else { isScat = (scatterBlocks > meanBlocks); rid = bid - 2 * nmin + nmin; }

    if (isScat) {
        int e = rid * 256 + tid;
        if (e < E) {
            int s = ei[e];
            int d = ei[E + e];
            float w = ea[(size_t)e * 16 + 15];   // lane e -> line e: sequential stream
            int p = atomicAdd(cur + d, 1);
            if (p < CAP) {
                eb[(size_t)d * CAP + p] = make_int2(s, __float_as_int(w));
            } else {
                int q = atomicAdd(ovf_cnt, 1);
                if (q < OVF_MAX) ovf[q] = make_int4(s, d, __float_as_int(w), 0);
            }
        }
        return;
    }
    __shared__ float4 Wt[16 * 64];           // 16KB, conflict-free layout
    __shared__ float rbuf[4 * 64];
    stage_W(W1, Wt, tid);
    __syncthreads();
    int w = tid >> 6, l = tid & 63;
    float* rw = rbuf + w * 64;
    for (int it = 0; it < 4; ++it) {         // NOT unrolled: keep VGPRs lean
        int n = rid * 16 + it * 4 + w;       // wave-uniform
        if (n >= N) continue;
        const float4* xp = (const float4*)(x + (size_t)n * 1024);
        float4 v0 = xp[l], v1 = xp[64 + l], v2 = xp[128 + l], v3 = xp[192 + l];
        float s0 = (v0.x + v0.y) + (v0.z + v0.w);
        float s1 = (v1.x + v1.y) + (v1.z + v1.w);
        float s2 = (v2.x + v2.y) + (v2.z + v2.w);
        float s3 = (v3.x + v3.y) + (v3.z + v3.w);
        s0 += __shfl_xor(s0, 1); s0 += __shfl_xor(s0, 2);
        s1 += __shfl_xor(s1, 1); s1 += __shfl_xor(s1, 2);
        s2 += __shfl_xor(s2, 1); s2 += __shfl_xor(s2, 2);
        s3 += __shfl_xor(s3, 1); s3 += __shfl_xor(s3, 2);
        if ((l & 3) == 0) {                  // quad leader: channels q,16+q,32+q,48+q
            int q = l >> 2;
            rw[q]      = s0 * 0.0625f;
            rw[q + 16] = s1 * 0.0625f;
            rw[q + 32] = s2 * 0.0625f;
            rw[q + 48] = s3 * 0.0625f;
        }
        float acc = 0.0f;
        const float4* rb4 = (const float4*)rw;
        #pragma unroll
        for (int q = 0; q < 16; ++q) {
            float4 rv = rb4[q];              // broadcast (same addr all lanes)
            float4 wv = Wt[q * 64 + l];      // contiguous: conflict-free
            acc = fmaf(rv.x, wv.x, acc);
            acc = fmaf(rv.y, wv.y, acc);
            acc = fmaf(rv.z, wv.z, acc);
            acc = fmaf(rv.w, wv.w, acc);
        }
        h1[(size_t)n * 64 + l] = acc;
    }
}

// Phase A: dinv[n] = 1/sqrt(1 + bucket ew sum), 4 lanes/node (64 nodes/block).
// Phase B: scale H1 *= dinv[n] in place (g-form: folds dinv[src] out of aggs).
__global__ __launch_bounds__(256) void k_dinvb(
        const int* __restrict__ cur, const int2* __restrict__ eb,
        const int* __restrict__ ovf_cnt, const int4* __restrict__ ovf,
        float* __restrict__ dinv, float* __restrict__ H1, int N) {
    __shared__ float sdv[64];
    int tid = threadIdx.x;
    int base = blockIdx.x * 64;
    int n = base + (tid >> 2);
    int j = tid & 3;
    if (n < N) {
        int mfull = cur[n];
        int m = mfull > CAP ? CAP : mfull;
        float s = 0.0f;
        for (int i = j; i < m; i += 4) s += __int_as_float(eb[(size_t)n * CAP + i].y);
        s += __shfl_xor(s, 1);
        s += __shfl_xor(s, 2);
        if (j == 0) {
            if (mfull > CAP) {
                int oc = *ovf_cnt; if (oc > OVF_MAX) oc = OVF_MAX;
                for (int k = 0; k < oc; ++k) {
                    int4 o = ovf[k];
                    if (o.y == n) s += __int_as_float(o.z);
                }
            }
            float dv = 1.0f / sqrtf(s + 1.0f);
            dinv[n] = dv;
            sdv[tid >> 2] = dv;
        }
    }
    __syncthreads();
    // phase B: 64 nodes x 64 ch = 4096 elems, 256 threads x 16 iters, coalesced
    #pragma unroll
    for (int k = 0; k < 16; ++k) {
        int idx = k * 256 + tid;
        int ln = idx >> 6, ch = idx & 63;
        int nn = base + ln;
        if (nn < N) H1[(size_t)nn * 64 + ch] *= sdv[ln];
    }
}

// Layer-1: gather g=H1*dinv + bias + relu; writes Zg = relu(r)*dinv (g-form).
__global__ __launch_bounds__(256) void k_agg1(const float* __restrict__ in,
                                              const float* __restrict__ bias,
                                              const float* __restrict__ dinv,
                                              const int* __restrict__ cur,
                                              const int2* __restrict__ eb,
                                              const int* __restrict__ ovf_cnt,
                                              const int4* __restrict__ ovf,
                                              float* __restrict__ out, int N) {
    int tid = threadIdx.x;
    int w = tid >> 6, c = tid & 63;
    float bias_c = bias[c];
    for (int it = 0; it < 4; ++it) {
        int n = blockIdx.x * 16 + it * 4 + w;
        if (n >= N) continue;
        float dv = dinv[n];
        float gself = in[(size_t)n * 64 + c];     // already dinv-scaled
        float a0 = 0.f, a1 = 0.f, a2 = 0.f, a3 = 0.f;
        int anyovf;
        GATHER_BODY(in, n, c, a0, a1, a2, a3, anyovf)
        float r = fmaf(dv, ((a0 + a1) + (a2 + a3)) + gself, bias_c);
        r = fmaxf(r, 0.0f);
        out[(size_t)n * 64 + c] = r * dv;         // Zg for layer 2
    }
}

// Layer-2: gather Zg + conflict-free LDS GEMM (Wc) + bc -> final output.
__global__ __launch_bounds__(256) void k_agg2(const float* __restrict__ in,
                                              const float* __restrict__ Wc,
                                              const float* __restrict__ bc,
                                              const float* __restrict__ dinv,
                                              const int* __restrict__ cur,
                                              const int2* __restrict__ eb,
                                              const int* __restrict__ ovf_cnt,
                                              const int4* __restrict__ ovf,
                                              float* __restrict__ out, int N) {
    __shared__ float4 Wt[16 * 64];
    __shared__ float rbuf[4 * 64];
    int tid = threadIdx.x;
    stage_W(Wc, Wt, tid);
    __syncthreads();
    int w = tid >> 6, c = tid & 63;
    float bc_c = bc[c];
    float* rw = rbuf + w * 64;
    for (int it = 0; it < 4; ++it) {         // NOT unrolled
        int n = blockIdx.x * 16 + it * 4 + w;
        if (n >= N) continue;
        float dv = dinv[n];
        float gself = in[(size_t)n * 64 + c];     // Zg, already dinv-scaled
        float a0 = 0.f, a1 = 0.f, a2 = 0.f, a3 = 0.f;
        int anyovf;
        GATHER_BODY(in, n, c, a0, a1, a2, a3, anyovf)
        float r = dv * (((a0 + a1) + (a2 + a3)) + gself);
        rw[c] = r;
        float acc = bc_c;
        const float4* rb4 = (const float4*)rw;
        #pragma unroll
        for (int q = 0; q < 16; ++q) {
            float4 rv = rb4[q];              // broadcast
            float4 wv = Wt[q * 64 + c];      // contiguous: conflict-free
            acc = fmaf(rv.x, wv.x, acc);
            acc = fmaf(rv.y, wv.y, acc);
            acc = fmaf(rv.z, wv.z, acc);
            acc = fmaf(rv.w, wv.w, acc);
        }
        out[(size_t)n * 64 + c] = acc;
    }
}

// ---------------- launcher ----------------

extern "C" void kernel_launch(void* const* d_in, const int* in_sizes, int n_in,
                              void* d_out, int out_size, void* d_ws, size_t ws_size,
                              hipStream_t stream) {
    const float* x    = (const float*)d_in[0];
    const int*   ei   = (const int*)d_in[1];
    const float* ea   = (const float*)d_in[2];
    const float* W1   = (const float*)d_in[3];
    const float* b1   = (const float*)d_in[4];
    const float* W2   = (const float*)d_in[5];
    const float* b2   = (const float*)d_in[6];
    const float* Wout = (const float*)d_in[7];
    const float* bout = (const float*)d_in[8];
    float* out = (float*)d_out;

    const int N = in_sizes[0] / (64 * 16);   // 50000
    const int E = in_sizes[1] / 2;           // 800000

    // workspace layout
    char* wsb = (char*)d_ws;
    int4*  ovf  = (int4*)wsb;                       // 128KB
    int2*  eb   = (int2*)(wsb + OVF_MAX * 16);      // N*CAP*8B = 25.6MB
    float* H1   = (float*)(wsb + OVF_MAX * 16 + (size_t)N * CAP * 8);
    size_t NC = (size_t)N * 64;
    float* Zg   = H1 + NC;
    int*   cur  = (int*)(Zg + NC);                  // N ints (dense — R12 null)
    int*   ovfc = cur + N;                          // adjacent: one memset covers both
    float* dinv = (float*)(ovfc + 16);
    float* Wc   = dinv + N;
    float* bc   = Wc + 4096;

    dim3 b256(256);
    int meanBlocks    = (N + 15) / 16;       // 3125
    int scatterBlocks = (E + 255) / 256;     // 3125 (1 edge/thread — proven config)

    // zero cur + ovfc in one async fill (replaces the k_pre zero phase)
    hipMemsetAsync(cur, 0, (size_t)(N + 16) * sizeof(int), stream);

    hipLaunchKernelGGL(k_scatmean,
                       dim3(scatterBlocks + meanBlocks + 17), b256, 0, stream,
                       ei, ea, cur, eb, ovfc, ovf, E, scatterBlocks,
                       x, W1, H1, N, meanBlocks, W2, Wout, b2, bout, Wc, bc);
    hipLaunchKernelGGL(k_dinvb, dim3((N + 63) / 64), b256, 0, stream,
                       cur, eb, ovfc, ovf, dinv, H1, N);
    // layer 1: Zg = relu(dv*(Σ g[src]*ew + g[n]) + b1) * dv
    hipLaunchKernelGGL(k_agg1, dim3(meanBlocks), b256, 0, stream,
                       H1, b1, dinv, cur, eb, ovfc, ovf, Zg, N);
    // layer 2+out: out = (dv*(Σ Zg[src]*ew + Zg[n])) @ Wc + bc
    hipLaunchKernelGGL(k_agg2, dim3(meanBlocks), b256, 0, stream,
                       Zg, Wc, bc, dinv, cur, eb, ovfc, ovf, out, N);
}